// Round 11
// baseline (157.247 us; speedup 1.0000x reference)
//
#include <hip/hip_runtime.h>
#include <hip/hip_bf16.h>

#define MODELS 64
#define BATCH 64
#define IN_DIM 512
#define UNITS 512
#define NCOLS 2048
// Packed-A: per tensor [m][ks16][kq4][row64] granules of 8 bf16 (16 B)
#define GRAN_PER_TENSOR (MODELS * 16 * 4 * 64)  // 262144 granules = 4 MB/tensor

typedef __attribute__((ext_vector_type(8))) short short8;
typedef __attribute__((ext_vector_type(4))) float f32x4;

static __device__ __forceinline__ short f2bf(float f) {
    return __builtin_bit_cast(short, __float2bfloat16(f));
}
static __device__ __forceinline__ float sigmoidf_(float x) {
    return 1.0f / (1.0f + __expf(-x));
}
static __device__ __forceinline__ float tanhf_(float x) {
    float e = __expf(-2.0f * fabsf(x));
    float r = (1.0f - e) / (1.0f + e);
    return copysignf(r, x);
}

// Re-layout inputs & h_tm1 (f32) into bf16 MFMA-A-fragment order (unchanged).
__global__ __launch_bounds__(256) void prepack_A_kernel(
    const float* __restrict__ x, const float* __restrict__ h,
    short8* __restrict__ P)
{
    const int t = blockIdx.x * 256 + threadIdx.x;   // [0, 2*262144)
    const int tensor = t >> 18;
    const int r = t & (GRAN_PER_TENSOR - 1);
    const int kg = r & 3;
    const int row = (r >> 2) & 63;
    const int ks = (r >> 8) & 15;
    const int m = r >> 12;
    const float* src = (tensor ? h : x) + ((size_t)(m * 64 + row) * 512 + ks * 32 + kg * 8);
    f32x4 a0 = *(const f32x4*)src;
    f32x4 a1 = *(const f32x4*)(src + 4);
    short8 v;
    v[0] = f2bf(a0[0]); v[1] = f2bf(a0[1]); v[2] = f2bf(a0[2]); v[3] = f2bf(a0[3]);
    v[4] = f2bf(a1[0]); v[5] = f2bf(a1[1]); v[6] = f2bf(a1[2]); v[7] = f2bf(a1[3]);
    P[(size_t)tensor * GRAN_PER_TENSOR + (size_t)((m * 16 + ks) * 4 + kg) * 64 + row] = v;
}

// 512 blocks (model x 8 tiles of 64 units) x 256 threads (4 waves), 2 blocks/CU.
// ZERO barriers: staging is WAVE-PRIVATE (each wave stages the 32k x 16u x 4g slice
// only IT reads; 8 KB/step, double-buffered). Per-wave vmcnt(12) pipeline.
// Wave owns 16 units x all 4 gates -> fully in-register epilogue.
__global__ __launch_bounds__(256, 2) void lstm_nobar_kernel(
    const float* __restrict__ c_tm1,
    const float* __restrict__ kernel_,
    const float* __restrict__ rkernel,
    const float* __restrict__ bias,
    const short8* __restrict__ Pa,
    float* __restrict__ out)
{
    __shared__ float lds[16384];  // 64 KB: 4 waves x 2 bufs x 2048 f32

    const int bid = blockIdx.x;
    const int m = bid >> 3;
    const int u0 = (bid & 7) * 64;

    const int tid = threadIdx.x;
    const int w = tid >> 6;          // wave 0..3
    const int lane = tid & 63;
    const int col16 = lane & 15;
    const int kq = lane >> 4;
    const int ucol = u0 + w * 16 + col16;   // unit column this lane owns

    float* wlds = lds + w * 4096;    // wave-private: 2 bufs x 2048 f32

    const float* wbase[2] = { kernel_ + (size_t)m * IN_DIM * NCOLS,
                              rkernel + (size_t)m * UNITS * NCOLS };
    const short8* pabase[2] = { Pa + (size_t)m * 4096,
                                Pa + GRAN_PER_TENSOR + (size_t)m * 4096 };

    // Stage source offsets. Instr j (0..7) stores 64 lanes' 16B slots linearly.
    // Stored slot q=lane holds TRUE slot q^((j&2)<<1) (involution; flips gate bit0
    // for j&2 so B-reads are 2-way/bank). Decode q' = rr(2)|g(2)|p(2):
    //   src f32 = (j*4+rr)*NCOLS + g*512 + u0 + w*16 + p*4
    int soff[8];
#pragma unroll
    for (int j = 0; j < 8; ++j) {
        const int q = lane ^ ((j & 2) << 1);
        const int rr = q >> 4, g = (q >> 2) & 3, p = q & 3;
        soff[j] = (j * 4 + rr) * NCOLS + g * 512 + u0 + w * 16 + p * 4;
    }

    f32x4 acc[4][4];                 // [batch-tile][gate]
#pragma unroll
    for (int bt = 0; bt < 4; ++bt)
#pragma unroll
        for (int g = 0; g < 4; ++g) acc[bt][g] = (f32x4){0.f, 0.f, 0.f, 0.f};

    auto STAGE = [&](int step, int bufsel) {
        const float* wb = wbase[step >> 4] + (size_t)(step & 15) * 32 * NCOLS;
#pragma unroll
        for (int j = 0; j < 8; ++j) {
            const float* src = wb + soff[j];
            float* dst = wlds + bufsel * 2048 + j * 256;  // wave-uniform; HW adds lane*16
            __builtin_amdgcn_global_load_lds(
                (const __attribute__((address_space(1))) void*)src,
                (__attribute__((address_space(3))) void*)dst, 16, 0, 0);
        }
    };
    auto LOADA = [&](int step, short8 (&af)[4]) {
        const short8* pb = pabase[step >> 4] + (size_t)((step & 15) * 4 + kq) * 64 + col16;
#pragma unroll
        for (int bt = 0; bt < 4; ++bt)
            asm volatile("global_load_dwordx4 %0, %1, off"
                         : "=v"(af[bt]) : "v"(pb + bt * 16) : "memory");
    };
    // B-frag read: row kr=kq*8+i -> j=kr>>2, rr=kr&3; slot=(rr<<4|g<<2|col16>>2)^((j&2)<<1)
    auto COMPUTE = [&](int bufsel, short8 (&af)[4]) {
        const float* lb = wlds + bufsel * 2048;
#pragma unroll
        for (int g = 0; g < 4; ++g) {
            short8 bfr;
#pragma unroll
            for (int i = 0; i < 8; ++i) {
                const int kr = kq * 8 + i;
                const int j = kr >> 2, rr = kr & 3;
                const int slot = ((rr << 4) | (g << 2) | (col16 >> 2)) ^ ((j & 2) << 1);
                bfr[i] = f2bf(lb[j * 256 + slot * 4 + (col16 & 3)]);
            }
#pragma unroll
            for (int bt = 0; bt < 4; ++bt)
                acc[bt][g] = __builtin_amdgcn_mfma_f32_16x16x32_bf16(
                    af[bt], bfr, acc[bt][g], 0, 0, 0);
        }
    };

#define WAITV(N, af)                                                         \
    asm volatile("s_waitcnt vmcnt(" #N ")"                                   \
                 : "+v"(af[0]), "+v"(af[1]), "+v"(af[2]), "+v"(af[3])        \
                 :: "memory")
#define LGKM0() asm volatile("s_waitcnt lgkmcnt(0)" ::: "memory")
#define SB0() __builtin_amdgcn_sched_barrier(0)

    short8 afA[4], afB[4];
    STAGE(0, 0);
    LOADA(0, afA);

    for (int sp = 0; sp < 16; ++sp) {
        const int te = 2 * sp;
        // step te: prefetch te+1 -> buf1/afB; compute buf0/afA
        LGKM0();                       // prior ds_reads of buf1 fully done (WAR guard)
        STAGE(te + 1, 1);
        LOADA(te + 1, afB);
        WAITV(12, afA);                // drain step-te loads (issued a full step ago)
        SB0();
        COMPUTE(0, afA);
        // step te+1: prefetch te+2 -> buf0/afA; compute buf1/afB
        if (sp < 15) {
            LGKM0();                   // prior ds_reads of buf0 fully done
            STAGE(te + 2, 0);
            LOADA(te + 2, afA);
            WAITV(12, afB);
        } else {
            WAITV(0, afB);
        }
        SB0();
        COMPUTE(1, afB);
    }

    // ---- fused gate epilogue, fully in-register (wave holds all 4 gates) ----
    const float* bp = bias + (size_t)m * NCOLS;
    const float bi = bp[0 * 512 + ucol];
    const float bff = bp[1 * 512 + ucol];
    const float bcc = bp[2 * 512 + ucol];
    const float bo = bp[3 * 512 + ucol];

    const size_t mbase = (size_t)m * (BATCH * UNITS);
    const float* cprev = c_tm1 + mbase;
    float* hout0 = out;
    float* hout1 = out + (size_t)MODELS * BATCH * UNITS;
    float* cout = out + 2 * (size_t)MODELS * BATCH * UNITS;

#pragma unroll
    for (int bt = 0; bt < 4; ++bt) {
#pragma unroll
        for (int r = 0; r < 4; ++r) {
            const int b = bt * 16 + kq * 4 + r;   // batch row (D layout)
            const float z0 = acc[bt][0][r] + bi;
            const float z1 = acc[bt][1][r] + bff;
            const float z2 = acc[bt][2][r] + bcc;
            const float z3 = acc[bt][3][r] + bo;
            const float ig = sigmoidf_(z0);
            const float fg = sigmoidf_(z1);
            const float cand = tanhf_(z2);
            const float og = sigmoidf_(z3);
            const size_t idx = (size_t)b * UNITS + ucol;
            const float c = fg * cprev[idx] + ig * cand;
            const float hh = og * tanhf_(c);
            hout0[mbase + idx] = hh;
            hout1[mbase + idx] = hh;
            cout[mbase + idx] = c;
        }
    }
}

extern "C" void kernel_launch(void* const* d_in, const int* in_sizes, int n_in,
                              void* d_out, int out_size, void* d_ws, size_t ws_size,
                              hipStream_t stream) {
    const float* inputs = (const float*)d_in[0];
    const float* h_tm1 = (const float*)d_in[1];
    const float* c_tm1 = (const float*)d_in[2];
    const float* kernel_ = (const float*)d_in[3];
    const float* rkernel = (const float*)d_in[4];
    const float* bias = (const float*)d_in[5];
    float* out = (float*)d_out;

    short8* P = (short8*)d_ws;  // 8 MB of scratch
    hipLaunchKernelGGL(prepack_A_kernel, dim3(2 * GRAN_PER_TENSOR / 256), dim3(256),
                       0, stream, inputs, h_tm1, P);
    hipLaunchKernelGGL(lstm_nobar_kernel, dim3(MODELS * 8), dim3(256), 0, stream,
                       c_tm1, kernel_, rkernel, bias, P, out);
}

// Round 12
// 134.340 us; speedup vs baseline: 1.1705x; 1.1705x over previous
//
#include <hip/hip_runtime.h>
#include <hip/hip_bf16.h>

#define MODELS 64
#define BATCH 64
#define IN_DIM 512
#define UNITS 512
#define NCOLS 2048
// Packed-A: per tensor [m][ks16][kq4][row64] granules of 8 bf16 (16 B)
#define GRAN_PER_TENSOR (MODELS * 16 * 4 * 64)  // 262144 granules = 4 MB/tensor

typedef __attribute__((ext_vector_type(8))) short short8;
typedef __attribute__((ext_vector_type(4))) float f32x4;

static __device__ __forceinline__ short f2bf(float f) {
    return __builtin_bit_cast(short, __float2bfloat16(f));
}
static __device__ __forceinline__ float sigmoidf_(float x) {
    return 1.0f / (1.0f + __expf(-x));
}
static __device__ __forceinline__ float tanhf_(float x) {
    float e = __expf(-2.0f * fabsf(x));
    float r = (1.0f - e) / (1.0f + e);
    return copysignf(r, x);
}

// Re-layout inputs & h_tm1 (f32) into bf16 MFMA-A-fragment order (unchanged).
__global__ __launch_bounds__(256) void prepack_A_kernel(
    const float* __restrict__ x, const float* __restrict__ h,
    short8* __restrict__ P)
{
    const int t = blockIdx.x * 256 + threadIdx.x;   // [0, 2*262144)
    const int tensor = t >> 18;
    const int r = t & (GRAN_PER_TENSOR - 1);
    const int kg = r & 3;
    const int row = (r >> 2) & 63;
    const int ks = (r >> 8) & 15;
    const int m = r >> 12;
    const float* src = (tensor ? h : x) + ((size_t)(m * 64 + row) * 512 + ks * 32 + kg * 8);
    f32x4 a0 = *(const f32x4*)src;
    f32x4 a1 = *(const f32x4*)(src + 4);
    short8 v;
    v[0] = f2bf(a0[0]); v[1] = f2bf(a0[1]); v[2] = f2bf(a0[2]); v[3] = f2bf(a0[3]);
    v[4] = f2bf(a1[0]); v[5] = f2bf(a1[1]); v[6] = f2bf(a1[2]); v[7] = f2bf(a1[3]);
    P[(size_t)tensor * GRAN_PER_TENSOR + (size_t)((m * 16 + ks) * 4 + kg) * 64 + row] = v;
}

// 512 blocks (model x 8 tiles of 64 units) x 256 threads (4 waves), 2 blocks/CU.
// r10 skeleton + block-cooperative A staging (kills the 4x redundant A loads):
// per step: 8 W-stage instrs (32 KB) + 1 A-stage instr (4 KB shared), vmcnt(9).
__global__ __launch_bounds__(256, 2) void lstm_main_kernel(
    const float* __restrict__ c_tm1,
    const float* __restrict__ kernel_,
    const float* __restrict__ rkernel,
    const float* __restrict__ bias,
    const short8* __restrict__ Pa,
    float* __restrict__ out)
{
    __shared__ float lds[18432];  // 72 KB: W dbuf 2x8192 f32 | A dbuf 2x1024 f32

    const int bid = blockIdx.x;
    const int m = bid >> 3;
    const int u0 = (bid & 7) * 64;

    const int tid = threadIdx.x;
    const int w = tid >> 6;          // wave 0..3
    const int lane = tid & 63;
    const int col16 = lane & 15;
    const int kq = lane >> 4;
    const int ucol = u0 + w * 16 + col16;   // unit column this lane owns

    const float* wbase[2] = { kernel_ + (size_t)m * IN_DIM * NCOLS,
                              rkernel + (size_t)m * UNITS * NCOLS };
    const short8* pabase[2] = { Pa + (size_t)m * 4096,
                                Pa + GRAN_PER_TENSOR + (size_t)m * 4096 };

    // W stage source offsets (f32, within a 32-row K-step): j = 0..7, row = j*4 + w.
    // stored granule q=lane holds source granule lane ^ (((row>>3)&1)<<2)  (involution)
    int soff[8];
#pragma unroll
    for (int j = 0; j < 8; ++j) {
        const int row = j * 4 + w;
        const int q = lane ^ ((((row >> 3) & 1)) << 2);
        const int g = q >> 4;        // gate
        const int cq = q & 15;       // 16B-granule within 256 B chunk
        soff[j] = row * NCOLS + g * 512 + u0 + cq * 4;
    }

    f32x4 acc[4][4];                 // [batch-tile][gate]
#pragma unroll
    for (int bt = 0; bt < 4; ++bt)
#pragma unroll
        for (int g = 0; g < 4; ++g) acc[bt][g] = (f32x4){0.f, 0.f, 0.f, 0.f};

    auto STAGE_W = [&](int step, int bufsel) {
        const float* wb = wbase[step >> 4] + (size_t)(step & 15) * 32 * NCOLS;
#pragma unroll
        for (int j = 0; j < 8; ++j) {
            const float* src = wb + soff[j];
            float* dst = lds + bufsel * 8192 + j * 1024 + w * 256;  // wave-uniform
            __builtin_amdgcn_global_load_lds(
                (const __attribute__((address_space(1))) void*)src,
                (__attribute__((address_space(3))) void*)dst, 16, 0, 0);
        }
    };
    // A: wave w stages kq-quarter w (1 KB contiguous) -> block shares the 4 KB step
    auto STAGE_A = [&](int step, int bufsel) {
        const short8* src = pabase[step >> 4] + (size_t)((step & 15) * 4 + w) * 64 + lane;
        float* dst = lds + 16384 + bufsel * 1024 + w * 256;         // wave-uniform
        __builtin_amdgcn_global_load_lds(
            (const __attribute__((address_space(1))) void*)src,
            (__attribute__((address_space(3))) void*)dst, 16, 0, 0);
    };
    // B-frag: col g*64 + w*16 + col16, rows kq*8+i, swizzle key (kq&1)<<4 (2-way max).
    // A-frag: granule (kq*64 + bt*16 + col16) from the shared A buffer.
    auto COMPUTE = [&](int bufsel) {
        const float* lb = lds + bufsel * 8192 + kq * 8 * 256;
        const short8* ab = (const short8*)(lds + 16384 + bufsel * 1024);
        short8 af[4];
#pragma unroll
        for (int bt = 0; bt < 4; ++bt) af[bt] = ab[kq * 64 + bt * 16 + col16];
        const int cb = w * 16 + col16;
#pragma unroll
        for (int g = 0; g < 4; ++g) {
            const int rd = (g * 64 + cb) ^ ((kq & 1) << 4);
            short8 bfr;
#pragma unroll
            for (int i = 0; i < 8; ++i) bfr[i] = f2bf(lb[rd + i * 256]);
#pragma unroll
            for (int bt = 0; bt < 4; ++bt)
                acc[bt][g] = __builtin_amdgcn_mfma_f32_16x16x32_bf16(
                    af[bt], bfr, acc[bt][g], 0, 0, 0);
        }
    };

#define WAITV(N) asm volatile("s_waitcnt vmcnt(" #N ")" ::: "memory")
#define BAR() asm volatile("s_barrier" ::: "memory")
#define LGKM0() asm volatile("s_waitcnt lgkmcnt(0)" ::: "memory")

    STAGE_W(0, 0);
    STAGE_A(0, 0);

    for (int sp = 0; sp < 16; ++sp) {
        const int te = 2 * sp;
        // step te: prefetch te+1 -> buf1; compute buf0
        STAGE_W(te + 1, 1);
        STAGE_A(te + 1, 1);
        WAITV(9); BAR();          // drain step-te's 9 (issued a full step ago)
        COMPUTE(0);
        LGKM0(); BAR();           // all waves done reading buf0 before re-staging it
        // step te+1: prefetch te+2 -> buf0; compute buf1
        if (sp < 15) {
            STAGE_W(te + 2, 0);
            STAGE_A(te + 2, 0);
            WAITV(9);
        } else {
            WAITV(0);
        }
        BAR();
        COMPUTE(1);
        LGKM0(); BAR();
    }

    // ---- fused gate epilogue, fully in-register (wave holds all 4 gates) ----
    const float* bp = bias + (size_t)m * NCOLS;
    const float bi = bp[0 * 512 + ucol];
    const float bff = bp[1 * 512 + ucol];
    const float bcc = bp[2 * 512 + ucol];
    const float bo = bp[3 * 512 + ucol];

    const size_t mbase = (size_t)m * (BATCH * UNITS);
    const float* cprev = c_tm1 + mbase;
    float* hout0 = out;
    float* hout1 = out + (size_t)MODELS * BATCH * UNITS;
    float* cout = out + 2 * (size_t)MODELS * BATCH * UNITS;

#pragma unroll
    for (int bt = 0; bt < 4; ++bt) {
#pragma unroll
        for (int r = 0; r < 4; ++r) {
            const int b = bt * 16 + kq * 4 + r;   // batch row (D layout)
            const float z0 = acc[bt][0][r] + bi;
            const float z1 = acc[bt][1][r] + bff;
            const float z2 = acc[bt][2][r] + bcc;
            const float z3 = acc[bt][3][r] + bo;
            const float ig = sigmoidf_(z0);
            const float fg = sigmoidf_(z1);
            const float cand = tanhf_(z2);
            const float og = sigmoidf_(z3);
            const size_t idx = (size_t)b * UNITS + ucol;
            const float c = fg * cprev[idx] + ig * cand;
            const float hh = og * tanhf_(c);
            hout0[mbase + idx] = hh;
            hout1[mbase + idx] = hh;
            cout[mbase + idx] = c;
        }
    }
}

extern "C" void kernel_launch(void* const* d_in, const int* in_sizes, int n_in,
                              void* d_out, int out_size, void* d_ws, size_t ws_size,
                              hipStream_t stream) {
    const float* inputs = (const float*)d_in[0];
    const float* h_tm1 = (const float*)d_in[1];
    const float* c_tm1 = (const float*)d_in[2];
    const float* kernel_ = (const float*)d_in[3];
    const float* rkernel = (const float*)d_in[4];
    const float* bias = (const float*)d_in[5];
    float* out = (float*)d_out;

    short8* P = (short8*)d_ws;  // 8 MB of scratch
    hipLaunchKernelGGL(prepack_A_kernel, dim3(2 * GRAN_PER_TENSOR / 256), dim3(256),
                       0, stream, inputs, h_tm1, P);
    hipLaunchKernelGGL(lstm_main_kernel, dim3(MODELS * 8), dim3(256), 0, stream,
                       c_tm1, kernel_, rkernel, bias, P, out);
}

// Round 13
// 116.629 us; speedup vs baseline: 1.3483x; 1.1519x over previous
//
#include <hip/hip_runtime.h>
#include <hip/hip_bf16.h>

#define MODELS 64
#define BATCH 64
#define IN_DIM 512
#define UNITS 512
#define NCOLS 2048
// Packed-A: per tensor [m][ks16][kq4][row64] granules of 8 bf16 (16 B)
#define GRAN_PER_TENSOR (MODELS * 16 * 4 * 64)  // 262144 granules = 4 MB/tensor

typedef __attribute__((ext_vector_type(8))) short short8;
typedef __attribute__((ext_vector_type(4))) float f32x4;

static __device__ __forceinline__ short f2bf(float f) {
    return __builtin_bit_cast(short, __float2bfloat16(f));
}
static __device__ __forceinline__ float sigmoidf_(float x) {
    return 1.0f / (1.0f + __expf(-x));
}
static __device__ __forceinline__ float tanhf_(float x) {
    float e = __expf(-2.0f * fabsf(x));
    float r = (1.0f - e) / (1.0f + e);
    return copysignf(r, x);
}

// Re-layout inputs & h_tm1 (f32) into bf16 MFMA-A-fragment order (unchanged).
__global__ __launch_bounds__(256) void prepack_A_kernel(
    const float* __restrict__ x, const float* __restrict__ h,
    short8* __restrict__ P)
{
    const int t = blockIdx.x * 256 + threadIdx.x;   // [0, 2*262144)
    const int tensor = t >> 18;
    const int r = t & (GRAN_PER_TENSOR - 1);
    const int kg = r & 3;
    const int row = (r >> 2) & 63;
    const int ks = (r >> 8) & 15;
    const int m = r >> 12;
    const float* src = (tensor ? h : x) + ((size_t)(m * 64 + row) * 512 + ks * 32 + kg * 8);
    f32x4 a0 = *(const f32x4*)src;
    f32x4 a1 = *(const f32x4*)(src + 4);
    short8 v;
    v[0] = f2bf(a0[0]); v[1] = f2bf(a0[1]); v[2] = f2bf(a0[2]); v[3] = f2bf(a0[3]);
    v[4] = f2bf(a1[0]); v[5] = f2bf(a1[1]); v[6] = f2bf(a1[2]); v[7] = f2bf(a1[3]);
    P[(size_t)tensor * GRAN_PER_TENSOR + (size_t)((m * 16 + ks) * 4 + kg) * 64 + row] = v;
}

// 512 blocks (model x 8 tiles of 64 units) x 256 threads (4 waves), 2 blocks/CU.
// r12 skeleton; SINGLE CHANGE: weight staging uses NT (non-temporal, aux=2)
// cache policy so the 512 MB weight stream bypasses/evicts-first in L2+MALL ->
// HBM sees the full dense linear stream instead of a random 58% line-subsample.
__global__ __launch_bounds__(256, 2) void lstm_main_kernel(
    const float* __restrict__ c_tm1,
    const float* __restrict__ kernel_,
    const float* __restrict__ rkernel,
    const float* __restrict__ bias,
    const short8* __restrict__ Pa,
    float* __restrict__ out)
{
    __shared__ float lds[18432];  // 72 KB: W dbuf 2x8192 f32 | A dbuf 2x1024 f32

    const int bid = blockIdx.x;
    const int m = bid >> 3;
    const int u0 = (bid & 7) * 64;

    const int tid = threadIdx.x;
    const int w = tid >> 6;          // wave 0..3
    const int lane = tid & 63;
    const int col16 = lane & 15;
    const int kq = lane >> 4;
    const int ucol = u0 + w * 16 + col16;   // unit column this lane owns

    const float* wbase[2] = { kernel_ + (size_t)m * IN_DIM * NCOLS,
                              rkernel + (size_t)m * UNITS * NCOLS };
    const short8* pabase[2] = { Pa + (size_t)m * 4096,
                                Pa + GRAN_PER_TENSOR + (size_t)m * 4096 };

    // W stage source offsets (f32, within a 32-row K-step): j = 0..7, row = j*4 + w.
    // stored granule q=lane holds source granule lane ^ (((row>>3)&1)<<2)  (involution)
    int soff[8];
#pragma unroll
    for (int j = 0; j < 8; ++j) {
        const int row = j * 4 + w;
        const int q = lane ^ ((((row >> 3) & 1)) << 2);
        const int g = q >> 4;        // gate
        const int cq = q & 15;       // 16B-granule within 256 B chunk
        soff[j] = row * NCOLS + g * 512 + u0 + cq * 4;
    }

    f32x4 acc[4][4];                 // [batch-tile][gate]
#pragma unroll
    for (int bt = 0; bt < 4; ++bt)
#pragma unroll
        for (int g = 0; g < 4; ++g) acc[bt][g] = (f32x4){0.f, 0.f, 0.f, 0.f};

    auto STAGE_W = [&](int step, int bufsel) {
        const float* wb = wbase[step >> 4] + (size_t)(step & 15) * 32 * NCOLS;
#pragma unroll
        for (int j = 0; j < 8; ++j) {
            const float* src = wb + soff[j];
            float* dst = lds + bufsel * 8192 + j * 1024 + w * 256;  // wave-uniform
            __builtin_amdgcn_global_load_lds(
                (const __attribute__((address_space(1))) void*)src,
                (__attribute__((address_space(3))) void*)dst, 16, 0, 2 /*NT*/);
        }
    };
    // A: wave w stages kq-quarter w (1 KB contiguous) -> block shares the 4 KB step
    auto STAGE_A = [&](int step, int bufsel) {
        const short8* src = pabase[step >> 4] + (size_t)((step & 15) * 4 + w) * 64 + lane;
        float* dst = lds + 16384 + bufsel * 1024 + w * 256;         // wave-uniform
        __builtin_amdgcn_global_load_lds(
            (const __attribute__((address_space(1))) void*)src,
            (__attribute__((address_space(3))) void*)dst, 16, 0, 0);
    };
    // B-frag: col g*64 + w*16 + col16, rows kq*8+i, swizzle key (kq&1)<<4 (2-way max).
    // A-frag: granule (kq*64 + bt*16 + col16) from the shared A buffer.
    auto COMPUTE = [&](int bufsel) {
        const float* lb = lds + bufsel * 8192 + kq * 8 * 256;
        const short8* ab = (const short8*)(lds + 16384 + bufsel * 1024);
        short8 af[4];
#pragma unroll
        for (int bt = 0; bt < 4; ++bt) af[bt] = ab[kq * 64 + bt * 16 + col16];
        const int cb = w * 16 + col16;
#pragma unroll
        for (int g = 0; g < 4; ++g) {
            const int rd = (g * 64 + cb) ^ ((kq & 1) << 4);
            short8 bfr;
#pragma unroll
            for (int i = 0; i < 8; ++i) bfr[i] = f2bf(lb[rd + i * 256]);
#pragma unroll
            for (int bt = 0; bt < 4; ++bt)
                acc[bt][g] = __builtin_amdgcn_mfma_f32_16x16x32_bf16(
                    af[bt], bfr, acc[bt][g], 0, 0, 0);
        }
    };

#define WAITV(N) asm volatile("s_waitcnt vmcnt(" #N ")" ::: "memory")
#define BAR() asm volatile("s_barrier" ::: "memory")
#define LGKM0() asm volatile("s_waitcnt lgkmcnt(0)" ::: "memory")

    STAGE_W(0, 0);
    STAGE_A(0, 0);

    for (int sp = 0; sp < 16; ++sp) {
        const int te = 2 * sp;
        // step te: prefetch te+1 -> buf1; compute buf0
        STAGE_W(te + 1, 1);
        STAGE_A(te + 1, 1);
        WAITV(9); BAR();          // drain step-te's 9 (issued a full step ago)
        COMPUTE(0);
        LGKM0(); BAR();           // all waves done reading buf0 before re-staging it
        // step te+1: prefetch te+2 -> buf0; compute buf1
        if (sp < 15) {
            STAGE_W(te + 2, 0);
            STAGE_A(te + 2, 0);
            WAITV(9);
        } else {
            WAITV(0);
        }
        BAR();
        COMPUTE(1);
        LGKM0(); BAR();
    }

    // ---- fused gate epilogue, fully in-register (wave holds all 4 gates) ----
    const float* bp = bias + (size_t)m * NCOLS;
    const float bi = bp[0 * 512 + ucol];
    const float bff = bp[1 * 512 + ucol];
    const float bcc = bp[2 * 512 + ucol];
    const float bo = bp[3 * 512 + ucol];

    const size_t mbase = (size_t)m * (BATCH * UNITS);
    const float* cprev = c_tm1 + mbase;
    float* hout0 = out;
    float* hout1 = out + (size_t)MODELS * BATCH * UNITS;
    float* cout = out + 2 * (size_t)MODELS * BATCH * UNITS;

#pragma unroll
    for (int bt = 0; bt < 4; ++bt) {
#pragma unroll
        for (int r = 0; r < 4; ++r) {
            const int b = bt * 16 + kq * 4 + r;   // batch row (D layout)
            const float z0 = acc[bt][0][r] + bi;
            const float z1 = acc[bt][1][r] + bff;
            const float z2 = acc[bt][2][r] + bcc;
            const float z3 = acc[bt][3][r] + bo;
            const float ig = sigmoidf_(z0);
            const float fg = sigmoidf_(z1);
            const float cand = tanhf_(z2);
            const float og = sigmoidf_(z3);
            const size_t idx = (size_t)b * UNITS + ucol;
            const float c = fg * cprev[idx] + ig * cand;
            const float hh = og * tanhf_(c);
            hout0[mbase + idx] = hh;
            hout1[mbase + idx] = hh;
            cout[mbase + idx] = c;
        }
    }
}

extern "C" void kernel_launch(void* const* d_in, const int* in_sizes, int n_in,
                              void* d_out, int out_size, void* d_ws, size_t ws_size,
                              hipStream_t stream) {
    const float* inputs = (const float*)d_in[0];
    const float* h_tm1 = (const float*)d_in[1];
    const float* c_tm1 = (const float*)d_in[2];
    const float* kernel_ = (const float*)d_in[3];
    const float* rkernel = (const float*)d_in[4];
    const float* bias = (const float*)d_in[5];
    float* out = (float*)d_out;

    short8* P = (short8*)d_ws;  // 8 MB of scratch
    hipLaunchKernelGGL(prepack_A_kernel, dim3(2 * GRAN_PER_TENSOR / 256), dim3(256),
                       0, stream, inputs, h_tm1, P);
    hipLaunchKernelGGL(lstm_main_kernel, dim3(MODELS * 8), dim3(256), 0, stream,
                       c_tm1, kernel_, rkernel, bias, P, out);
}

// Round 14
// 110.707 us; speedup vs baseline: 1.4204x; 1.0535x over previous
//
#include <hip/hip_runtime.h>
#include <hip/hip_bf16.h>

#define MODELS 64
#define BATCH 64
#define IN_DIM 512
#define UNITS 512
#define NCOLS 2048
// Packed-A: per tensor [m][ks16][kq4][row64] granules of 8 bf16 (16 B)
#define GRAN_PER_TENSOR (MODELS * 16 * 4 * 64)  // 262144 granules = 4 MB/tensor
#define CACHED_MODELS 20   // first 20 models' weights (160 MB) use normal policy

typedef __attribute__((ext_vector_type(8))) short short8;
typedef __attribute__((ext_vector_type(4))) float f32x4;

static __device__ __forceinline__ short f2bf(float f) {
    return __builtin_bit_cast(short, __float2bfloat16(f));
}
static __device__ __forceinline__ float sigmoidf_(float x) {
    return 1.0f / (1.0f + __expf(-x));
}
static __device__ __forceinline__ float tanhf_(float x) {
    float e = __expf(-2.0f * fabsf(x));
    float r = (1.0f - e) / (1.0f + e);
    return copysignf(r, x);
}

// Re-layout inputs & h_tm1 (f32) into bf16 MFMA-A-fragment order (unchanged).
__global__ __launch_bounds__(256) void prepack_A_kernel(
    const float* __restrict__ x, const float* __restrict__ h,
    short8* __restrict__ P)
{
    const int t = blockIdx.x * 256 + threadIdx.x;   // [0, 2*262144)
    const int tensor = t >> 18;
    const int r = t & (GRAN_PER_TENSOR - 1);
    const int kg = r & 3;
    const int row = (r >> 2) & 63;
    const int ks = (r >> 8) & 15;
    const int m = r >> 12;
    const float* src = (tensor ? h : x) + ((size_t)(m * 64 + row) * 512 + ks * 32 + kg * 8);
    f32x4 a0 = *(const f32x4*)src;
    f32x4 a1 = *(const f32x4*)(src + 4);
    short8 v;
    v[0] = f2bf(a0[0]); v[1] = f2bf(a0[1]); v[2] = f2bf(a0[2]); v[3] = f2bf(a0[3]);
    v[4] = f2bf(a1[0]); v[5] = f2bf(a1[1]); v[6] = f2bf(a1[2]); v[7] = f2bf(a1[3]);
    P[(size_t)tensor * GRAN_PER_TENSOR + (size_t)((m * 16 + ks) * 4 + kg) * 64 + row] = v;
}

// 512 blocks (model x 8 tiles of 64 units) x 256 threads (4 waves), 2 blocks/CU.
// r13 skeleton; SINGLE CHANGE: weights of models < CACHED_MODELS use NORMAL
// cache policy (MALL-resident across graph replays, served at L3 BW); the rest
// stay NT (dense linear HBM stream). Manual L3 partitioning.
__global__ __launch_bounds__(256, 2) void lstm_main_kernel(
    const float* __restrict__ c_tm1,
    const float* __restrict__ kernel_,
    const float* __restrict__ rkernel,
    const float* __restrict__ bias,
    const short8* __restrict__ Pa,
    float* __restrict__ out)
{
    __shared__ float lds[18432];  // 72 KB: W dbuf 2x8192 f32 | A dbuf 2x1024 f32

    const int bid = blockIdx.x;
    const int m = bid >> 3;
    const int u0 = (bid & 7) * 64;
    const bool cacheW = (m < CACHED_MODELS);

    const int tid = threadIdx.x;
    const int w = tid >> 6;          // wave 0..3
    const int lane = tid & 63;
    const int col16 = lane & 15;
    const int kq = lane >> 4;
    const int ucol = u0 + w * 16 + col16;   // unit column this lane owns

    const float* wbase[2] = { kernel_ + (size_t)m * IN_DIM * NCOLS,
                              rkernel + (size_t)m * UNITS * NCOLS };
    const short8* pabase[2] = { Pa + (size_t)m * 4096,
                                Pa + GRAN_PER_TENSOR + (size_t)m * 4096 };

    // W stage source offsets (f32, within a 32-row K-step): j = 0..7, row = j*4 + w.
    // stored granule q=lane holds source granule lane ^ (((row>>3)&1)<<2)  (involution)
    int soff[8];
#pragma unroll
    for (int j = 0; j < 8; ++j) {
        const int row = j * 4 + w;
        const int q = lane ^ ((((row >> 3) & 1)) << 2);
        const int g = q >> 4;        // gate
        const int cq = q & 15;       // 16B-granule within 256 B chunk
        soff[j] = row * NCOLS + g * 512 + u0 + cq * 4;
    }

    f32x4 acc[4][4];                 // [batch-tile][gate]
#pragma unroll
    for (int bt = 0; bt < 4; ++bt)
#pragma unroll
        for (int g = 0; g < 4; ++g) acc[bt][g] = (f32x4){0.f, 0.f, 0.f, 0.f};

    auto STAGE_W = [&](int step, int bufsel) {
        const float* wb = wbase[step >> 4] + (size_t)(step & 15) * 32 * NCOLS;
#pragma unroll
        for (int j = 0; j < 8; ++j) {
            const float* src = wb + soff[j];
            float* dst = lds + bufsel * 8192 + j * 1024 + w * 256;  // wave-uniform
            if (cacheW) {
                __builtin_amdgcn_global_load_lds(
                    (const __attribute__((address_space(1))) void*)src,
                    (__attribute__((address_space(3))) void*)dst, 16, 0, 0);
            } else {
                __builtin_amdgcn_global_load_lds(
                    (const __attribute__((address_space(1))) void*)src,
                    (__attribute__((address_space(3))) void*)dst, 16, 0, 2 /*NT*/);
            }
        }
    };
    // A: wave w stages kq-quarter w (1 KB contiguous) -> block shares the 4 KB step
    auto STAGE_A = [&](int step, int bufsel) {
        const short8* src = pabase[step >> 4] + (size_t)((step & 15) * 4 + w) * 64 + lane;
        float* dst = lds + 16384 + bufsel * 1024 + w * 256;         // wave-uniform
        __builtin_amdgcn_global_load_lds(
            (const __attribute__((address_space(1))) void*)src,
            (__attribute__((address_space(3))) void*)dst, 16, 0, 0);
    };
    // B-frag: col g*64 + w*16 + col16, rows kq*8+i, swizzle key (kq&1)<<4 (2-way max).
    // A-frag: granule (kq*64 + bt*16 + col16) from the shared A buffer.
    auto COMPUTE = [&](int bufsel) {
        const float* lb = lds + bufsel * 8192 + kq * 8 * 256;
        const short8* ab = (const short8*)(lds + 16384 + bufsel * 1024);
        short8 af[4];
#pragma unroll
        for (int bt = 0; bt < 4; ++bt) af[bt] = ab[kq * 64 + bt * 16 + col16];
        const int cb = w * 16 + col16;
#pragma unroll
        for (int g = 0; g < 4; ++g) {
            const int rd = (g * 64 + cb) ^ ((kq & 1) << 4);
            short8 bfr;
#pragma unroll
            for (int i = 0; i < 8; ++i) bfr[i] = f2bf(lb[rd + i * 256]);
#pragma unroll
            for (int bt = 0; bt < 4; ++bt)
                acc[bt][g] = __builtin_amdgcn_mfma_f32_16x16x32_bf16(
                    af[bt], bfr, acc[bt][g], 0, 0, 0);
        }
    };

#define WAITV(N) asm volatile("s_waitcnt vmcnt(" #N ")" ::: "memory")
#define BAR() asm volatile("s_barrier" ::: "memory")
#define LGKM0() asm volatile("s_waitcnt lgkmcnt(0)" ::: "memory")

    STAGE_W(0, 0);
    STAGE_A(0, 0);

    for (int sp = 0; sp < 16; ++sp) {
        const int te = 2 * sp;
        // step te: prefetch te+1 -> buf1; compute buf0
        STAGE_W(te + 1, 1);
        STAGE_A(te + 1, 1);
        WAITV(9); BAR();          // drain step-te's 9 (issued a full step ago)
        COMPUTE(0);
        LGKM0(); BAR();           // all waves done reading buf0 before re-staging it
        // step te+1: prefetch te+2 -> buf0; compute buf1
        if (sp < 15) {
            STAGE_W(te + 2, 0);
            STAGE_A(te + 2, 0);
            WAITV(9);
        } else {
            WAITV(0);
        }
        BAR();
        COMPUTE(1);
        LGKM0(); BAR();
    }

    // ---- fused gate epilogue, fully in-register (wave holds all 4 gates) ----
    const float* bp = bias + (size_t)m * NCOLS;
    const float bi = bp[0 * 512 + ucol];
    const float bff = bp[1 * 512 + ucol];
    const float bcc = bp[2 * 512 + ucol];
    const float bo = bp[3 * 512 + ucol];

    const size_t mbase = (size_t)m * (BATCH * UNITS);
    const float* cprev = c_tm1 + mbase;
    float* hout0 = out;
    float* hout1 = out + (size_t)MODELS * BATCH * UNITS;
    float* cout = out + 2 * (size_t)MODELS * BATCH * UNITS;

#pragma unroll
    for (int bt = 0; bt < 4; ++bt) {
#pragma unroll
        for (int r = 0; r < 4; ++r) {
            const int b = bt * 16 + kq * 4 + r;   // batch row (D layout)
            const float z0 = acc[bt][0][r] + bi;
            const float z1 = acc[bt][1][r] + bff;
            const float z2 = acc[bt][2][r] + bcc;
            const float z3 = acc[bt][3][r] + bo;
            const float ig = sigmoidf_(z0);
            const float fg = sigmoidf_(z1);
            const float cand = tanhf_(z2);
            const float og = sigmoidf_(z3);
            const size_t idx = (size_t)b * UNITS + ucol;
            const float c = fg * cprev[idx] + ig * cand;
            const float hh = og * tanhf_(c);
            hout0[mbase + idx] = hh;
            hout1[mbase + idx] = hh;
            cout[mbase + idx] = c;
        }
    }
}

extern "C" void kernel_launch(void* const* d_in, const int* in_sizes, int n_in,
                              void* d_out, int out_size, void* d_ws, size_t ws_size,
                              hipStream_t stream) {
    const float* inputs = (const float*)d_in[0];
    const float* h_tm1 = (const float*)d_in[1];
    const float* c_tm1 = (const float*)d_in[2];
    const float* kernel_ = (const float*)d_in[3];
    const float* rkernel = (const float*)d_in[4];
    const float* bias = (const float*)d_in[5];
    float* out = (float*)d_out;

    short8* P = (short8*)d_ws;  // 8 MB of scratch
    hipLaunchKernelGGL(prepack_A_kernel, dim3(2 * GRAN_PER_TENSOR / 256), dim3(256),
                       0, stream, inputs, h_tm1, P);
    hipLaunchKernelGGL(lstm_main_kernel, dim3(MODELS * 8), dim3(256), 0, stream,
                       c_tm1, kernel_, rkernel, bias, P, out);
}